// Round 2
// baseline (457.285 us; speedup 1.0000x reference)
//
#include <hip/hip_runtime.h>
#include <hip/hip_bf16.h>

#define EPSF 1e-5f

typedef __bf16 bf16x8 __attribute__((ext_vector_type(8)));
typedef float f32x4 __attribute__((ext_vector_type(4)));

__device__ __forceinline__ float softplus_f(float x) {
  return fmaxf(x, 0.0f) + log1pf(expf(-fabsf(x)));
}

__device__ __forceinline__ unsigned short f2bf_bits(float f) {
  union { float f; unsigned int u; } v; v.f = f;
  unsigned int u = v.u;
  unsigned int lsb = (u >> 16) & 1u;
  u += 0x7fffu + lsb;  // round-to-nearest-even
  return (unsigned short)(u >> 16);
}

__device__ __forceinline__ void gl2lds16(const void* g, void* l) {
  __builtin_amdgcn_global_load_lds((const __attribute__((address_space(1))) void*)g,
                                   (__attribute__((address_space(3))) void*)l,
                                   16, 0, 0);
}

// ---------------- graph prep ----------------
// wsum[e] = sum_b max(adj[b,src,dst], adj[b,dst,src]) ; 64 blocks x 8 edges
__global__ __launch_bounds__(256) void k_wsum(const float* __restrict__ adj,
                                              const int* __restrict__ eidx,
                                              float* __restrict__ wsum) {
  __shared__ float part[256];
  int g = blockIdx.x;
  int t = threadIdx.x;
  int el = t & 7;
  int e = g * 8 + el;
  int s = eidx[e], d = eidx[512 + e];
  int boff = t >> 3;  // 0..31
  float acc = 0.f;
  for (int i = 0; i < 8; i++) {
    int b = boff + 32 * i;
    int base = b * 4096;
    float w1 = adj[base + s * 64 + d];
    float w2 = adj[base + d * 64 + s];
    acc += fmaxf(w1, w2);
  }
  part[t] = acc;
  __syncthreads();
  if (t < 8) {
    float sum = 0.f;
    for (int i = t; i < 256; i += 8) sum += part[i];
    wsum[g * 8 + t] = sum;
  }
}

// S[dst,src] += -dinv[src]*wsum*dinv[dst]
__global__ __launch_bounds__(512) void k_S(const int* __restrict__ eidx,
                                           const float* __restrict__ wsum,
                                           float* __restrict__ S) {
  __shared__ float deg[64];
  __shared__ float Ssh[4096];
  int t = threadIdx.x;
  if (t < 64) deg[t] = 0.f;
  for (int i = t; i < 4096; i += 512) Ssh[i] = 0.f;
  __syncthreads();
  int s = eidx[t], d = eidx[512 + t];
  float w = wsum[t];
  atomicAdd(&deg[s], w);
  __syncthreads();
  float ds = deg[s], dd = deg[d];
  float dis = ds > 0.f ? 1.0f / sqrtf(ds) : 0.f;
  float did = dd > 0.f ? 1.0f / sqrtf(dd) : 0.f;
  float coef = -dis * w * did;
  atomicAdd(&Ssh[d * 64 + s], coef);
  __syncthreads();
  for (int i = t; i < 4096; i += 512) S[i] = Ssh[i];
}

// h1 = S @ x[:64]
__global__ __launch_bounds__(256) void k_h1(const float* __restrict__ S,
                                            const float* __restrict__ x,
                                            float* __restrict__ h1) {
  int idx = blockIdx.x * 256 + threadIdx.x;
  if (idx >= 64 * 657) return;
  int i = idx / 657, f = idx - i * 657;
  float acc = 0.f;
  for (int j = 0; j < 64; j++) acc += S[i * 64 + j] * x[j * 657 + f];
  h1[idx] = acc;
}

// h2 = 2*(S @ h1)
__global__ __launch_bounds__(256) void k_h2(const float* __restrict__ S,
                                            const float* __restrict__ h1,
                                            float* __restrict__ h2) {
  int idx = blockIdx.x * 256 + threadIdx.x;
  if (idx >= 64 * 657) return;
  int i = idx / 657, f = idx - i * 657;
  float acc = 0.f;
  for (int j = 0; j < 64; j++) acc += S[i * 64 + j] * h1[j * 657 + f];
  h2[idx] = 2.f * acc;
}

// hc = h1 @ W1 + h2 @ W2
__global__ __launch_bounds__(256) void k_hc(const float* __restrict__ h1,
                                            const float* __restrict__ h2,
                                            const float* __restrict__ cheb_w,
                                            float* __restrict__ hc) {
  int idx = blockIdx.x * 256 + threadIdx.x;
  if (idx >= 64 * 657) return;
  int i = idx / 657, f = idx - i * 657;
  const float* W1 = cheb_w + 657 * 657;
  const float* W2 = cheb_w + 2 * 657 * 657;
  float acc = 0.f;
  for (int k = 0; k < 657; k++) {
    acc += h1[i * 657 + k] * W1[k * 657 + f];
    acc += h2[i * 657 + k] * W2[k * 657 + f];
  }
  hc[idx] = acc;
}

// xf_pad: 16384 x 672 bf16 (zero-fill k>=657), converted from fp32
__global__ __launch_bounds__(256) void k_pad(const float* __restrict__ x,
                                             unsigned short* __restrict__ xp) {
  int idx = blockIdx.x * 256 + threadIdx.x;  // exactly 16384*672 threads
  int rr = idx / 672, k = idx - rr * 672;
  unsigned short v = 0;
  if (k < 657) v = f2bf_bits(x[rr * 657 + k]);
  xp[idx] = v;
}

// WdT_pad[n][k] = W0[k][n] - W2[k][n], 768 x 672 bf16 zero-padded
__global__ __launch_bounds__(256) void k_wdt(const float* __restrict__ cheb_w,
                                             unsigned short* __restrict__ wt) {
  int idx = blockIdx.x * 256 + threadIdx.x;  // exactly 768*672
  int n = idx / 672, k = idx - n * 672;
  float v = 0.f;
  if (n < 657 && k < 657)
    v = cheb_w[k * 657 + n] - cheb_w[2 * 657 * 657 + k * 657 + n];
  wt[idx] = f2bf_bits(v);
}

// ---------------- main GEMM: out1 = bn1(softplus(xf@Wd + cheb_b [+ hc rows<64])) ----------------
__global__ __launch_bounds__(256) void k_gemm_main(
    const unsigned short* __restrict__ Ap,   // 16384 x 672 bf16
    const unsigned short* __restrict__ BT,   // 768 x 672 bf16 (row n holds Wd[:,n])
    const float* __restrict__ hc,            // 64 x 657
    const float* __restrict__ cheb_b,
    const float* __restrict__ bn1,           // 4 x 657
    unsigned short* __restrict__ out1) {     // 16384 x 657 bf16
  __shared__ __align__(16) unsigned short As[128 * 32];
  __shared__ __align__(16) unsigned short Bs[128 * 32];
  const int mBase = blockIdx.x * 128;
  const int nBase = blockIdx.y * 128;
  const int tid = threadIdx.x;
  const int wave = tid >> 6, lane = tid & 63;
  const int wm = (wave >> 1) * 64, wn = (wave & 1) * 64;
  const int q = lane >> 4, r = lane & 15;
  f32x4 acc[4][4] = {};
  for (int k0 = 0; k0 < 672; k0 += 32) {
#pragma unroll
    for (int i = 0; i < 2; i++) {
      int c = i * 256 + tid;
      int row = c >> 2, kg = (c & 3) * 8;
      gl2lds16(Ap + (size_t)(mBase + row) * 672 + k0 + kg, &As[c * 8]);
      gl2lds16(BT + (size_t)(nBase + row) * 672 + k0 + kg, &Bs[c * 8]);
    }
    __syncthreads();
    bf16x8 a[4], b[4];
#pragma unroll
    for (int mi = 0; mi < 4; mi++)
      a[mi] = *(const bf16x8*)&As[(wm + mi * 16 + r) * 32 + q * 8];
#pragma unroll
    for (int ni = 0; ni < 4; ni++)
      b[ni] = *(const bf16x8*)&Bs[(wn + ni * 16 + r) * 32 + q * 8];
#pragma unroll
    for (int mi = 0; mi < 4; mi++)
#pragma unroll
      for (int ni = 0; ni < 4; ni++)
        acc[mi][ni] = __builtin_amdgcn_mfma_f32_16x16x32_bf16(a[mi], b[ni], acc[mi][ni], 0, 0, 0);
    __syncthreads();
  }
#pragma unroll
  for (int ni = 0; ni < 4; ni++) {
    int f = nBase + wn + ni * 16 + r;
    if (f >= 657) continue;
    float cb = cheb_b[f];
    float g1 = bn1[f], b1 = bn1[657 + f];
    float m1 = bn1[2 * 657 + f], v1 = bn1[3 * 657 + f];
    float inv = 1.0f / sqrtf(v1 + EPSF);
#pragma unroll
    for (int mi = 0; mi < 4; mi++) {
#pragma unroll
      for (int p = 0; p < 4; p++) {
        int row = mBase + wm + mi * 16 + q * 4 + p;
        float v = acc[mi][ni][p] + cb;
        if (row < 64) v += hc[row * 657 + f];
        v = softplus_f(v);
        v = g1 * (v - m1) * inv + b1;
        out1[(size_t)row * 657 + f] = f2bf_bits(v);
      }
    }
  }
}

// ---------------- fc1 GEMM split-K: Cacc += out1(256x42048) @ fc1_w(42048x256) ----------------
__global__ __launch_bounds__(256) void k_gemm_fc1(
    const unsigned short* __restrict__ A,    // 256 x 42048 bf16
    const float* __restrict__ W,             // 42048 x 256 fp32
    float* __restrict__ Cacc) {              // 256 x 256, pre-zeroed
  __shared__ __align__(16) unsigned short As[128 * 32];
  __shared__ __align__(16) unsigned short Bs[128 * 32];  // Bs[n][k]
  const int mBase = blockIdx.x * 128;
  const int nBase = blockIdx.y * 128;
  const int kc0 = blockIdx.z * 2336;  // 18 * 2336 = 42048
  const int tid = threadIdx.x;
  const int wave = tid >> 6, lane = tid & 63;
  const int wm = (wave >> 1) * 64, wn = (wave & 1) * 64;
  const int q = lane >> 4, r = lane & 15;
  f32x4 acc[4][4] = {};
  for (int kt = 0; kt < 73; kt++) {
    int k0 = kc0 + kt * 32;
#pragma unroll
    for (int i = 0; i < 2; i++) {
      int c = i * 256 + tid;
      int row = c >> 2, kg = (c & 3) * 8;
      gl2lds16(A + (size_t)(mBase + row) * 42048 + k0 + kg, &As[c * 8]);
    }
    {
      int kl = tid >> 4, ng = tid & 15;  // kl 0..31 (tid<512 -> need 2 k per thread? no: 256 threads)
      // 256 threads: each stages 16 elements: 2 k-rows x 8 n
      int kl0 = (tid >> 4) * 2;          // 0,2,..,30
      const float4* wp0 = (const float4*)(W + (size_t)(k0 + kl0) * 256 + nBase + ng * 8);
      const float4* wp1 = (const float4*)(W + (size_t)(k0 + kl0 + 1) * 256 + nBase + ng * 8);
      float4 v0a = wp0[0], v0b = wp0[1];
      float4 v1a = wp1[0], v1b = wp1[1];
      int nb = ng * 8;
      Bs[(nb + 0) * 32 + kl0] = f2bf_bits(v0a.x);
      Bs[(nb + 1) * 32 + kl0] = f2bf_bits(v0a.y);
      Bs[(nb + 2) * 32 + kl0] = f2bf_bits(v0a.z);
      Bs[(nb + 3) * 32 + kl0] = f2bf_bits(v0a.w);
      Bs[(nb + 4) * 32 + kl0] = f2bf_bits(v0b.x);
      Bs[(nb + 5) * 32 + kl0] = f2bf_bits(v0b.y);
      Bs[(nb + 6) * 32 + kl0] = f2bf_bits(v0b.z);
      Bs[(nb + 7) * 32 + kl0] = f2bf_bits(v0b.w);
      Bs[(nb + 0) * 32 + kl0 + 1] = f2bf_bits(v1a.x);
      Bs[(nb + 1) * 32 + kl0 + 1] = f2bf_bits(v1a.y);
      Bs[(nb + 2) * 32 + kl0 + 1] = f2bf_bits(v1a.z);
      Bs[(nb + 3) * 32 + kl0 + 1] = f2bf_bits(v1a.w);
      Bs[(nb + 4) * 32 + kl0 + 1] = f2bf_bits(v1b.x);
      Bs[(nb + 5) * 32 + kl0 + 1] = f2bf_bits(v1b.y);
      Bs[(nb + 6) * 32 + kl0 + 1] = f2bf_bits(v1b.z);
      Bs[(nb + 7) * 32 + kl0 + 1] = f2bf_bits(v1b.w);
    }
    __syncthreads();
    bf16x8 a[4], b[4];
#pragma unroll
    for (int mi = 0; mi < 4; mi++)
      a[mi] = *(const bf16x8*)&As[(wm + mi * 16 + r) * 32 + q * 8];
#pragma unroll
    for (int ni = 0; ni < 4; ni++)
      b[ni] = *(const bf16x8*)&Bs[(wn + ni * 16 + r) * 32 + q * 8];
#pragma unroll
    for (int mi = 0; mi < 4; mi++)
#pragma unroll
      for (int ni = 0; ni < 4; ni++)
        acc[mi][ni] = __builtin_amdgcn_mfma_f32_16x16x32_bf16(a[mi], b[ni], acc[mi][ni], 0, 0, 0);
    __syncthreads();
  }
#pragma unroll
  for (int ni = 0; ni < 4; ni++) {
    int col = nBase + wn + ni * 16 + r;
#pragma unroll
    for (int mi = 0; mi < 4; mi++)
#pragma unroll
      for (int p = 0; p < 4; p++) {
        int row = mBase + wm + mi * 16 + q * 4 + p;
        atomicAdd(&Cacc[row * 256 + col], acc[mi][ni][p]);
      }
  }
}

// ---------------- tail: bn/softplus + fc2 + fc3 + softmax, one block per batch row ----------------
__global__ __launch_bounds__(256) void k_final(
    const float* __restrict__ Cacc,
    const float* __restrict__ fc1_b,
    const float* __restrict__ bnf1,
    const float* __restrict__ fc2_w,
    const float* __restrict__ fc2_b,
    const float* __restrict__ bnf2,
    const float* __restrict__ fc3_w,
    const float* __restrict__ fc3_b,
    const float* __restrict__ bnf3,
    float* __restrict__ out) {
  __shared__ float a1[256];
  __shared__ float a2[32];
  __shared__ float z[4];
  int b = blockIdx.x, t = threadIdx.x;
  {
    float v = Cacc[b * 256 + t] + fc1_b[t];
    v = softplus_f(v);
    float g = bnf1[t], bb = bnf1[256 + t];
    float m = bnf1[512 + t], vv = bnf1[768 + t];
    a1[t] = g * (v - m) / sqrtf(vv + EPSF) + bb;
  }
  __syncthreads();
  if (t < 32) {
    float s = fc2_b[t];
    for (int k = 0; k < 256; k++) s += a1[k] * fc2_w[k * 32 + t];
    s = softplus_f(s);
    float g = bnf2[t], bb = bnf2[32 + t];
    float m = bnf2[64 + t], vv = bnf2[96 + t];
    a2[t] = g * (s - m) / sqrtf(vv + EPSF) + bb;
  }
  __syncthreads();
  if (t < 4) {
    float s = fc3_b[t];
    for (int k = 0; k < 32; k++) s += a2[k] * fc3_w[k * 4 + t];
    float g = bnf3[t], bb = bnf3[4 + t];
    float m = bnf3[8 + t], vv = bnf3[12 + t];
    s = g * (s - m) / sqrtf(vv + EPSF) + bb;  // bn BEFORE softplus here
    z[t] = softplus_f(s);
  }
  __syncthreads();
  if (t == 0) {
    float mx = fmaxf(fmaxf(z[0], z[1]), fmaxf(z[2], z[3]));
    float e0 = expf(z[0] - mx), e1 = expf(z[1] - mx);
    float e2 = expf(z[2] - mx), e3 = expf(z[3] - mx);
    float inv = 1.0f / (e0 + e1 + e2 + e3);
    out[b * 4 + 0] = e0 * inv;
    out[b * 4 + 1] = e1 * inv;
    out[b * 4 + 2] = e2 * inv;
    out[b * 4 + 3] = e3 * inv;
  }
}

extern "C" void kernel_launch(void* const* d_in, const int* in_sizes, int n_in,
                              void* d_out, int out_size, void* d_ws, size_t ws_size,
                              hipStream_t stream) {
  const float* x      = (const float*)d_in[0];
  const float* adj    = (const float*)d_in[1];
  const int*   eidx   = (const int*)d_in[2];
  const float* cheb_w = (const float*)d_in[3];
  const float* cheb_b = (const float*)d_in[4];
  const float* fc1_w  = (const float*)d_in[5];
  const float* fc1_b  = (const float*)d_in[6];
  const float* fc2_w  = (const float*)d_in[7];
  const float* fc2_b  = (const float*)d_in[8];
  const float* fc3_w  = (const float*)d_in[9];
  const float* fc3_b  = (const float*)d_in[10];
  const float* bn1    = (const float*)d_in[11];
  const float* bnf1   = (const float*)d_in[12];
  const float* bnf2   = (const float*)d_in[13];
  const float* bnf3   = (const float*)d_in[14];

  char* ws = (char*)d_ws;
  float* S       = (float*)(ws + 0);          // 16384 B
  float* wsum    = (float*)(ws + 16384);      // 2048 B
  float* h1      = (float*)(ws + 18432);      // 168192 B
  float* h2      = (float*)(ws + 186624);     // 168192 B
  float* hc      = (float*)(ws + 354816);     // 168192 B
  float* fc1_acc = (float*)(ws + 523008);     // 262144 B
  unsigned short* xpad = (unsigned short*)(ws + 785152);      // 22020096 B
  unsigned short* wdt  = (unsigned short*)(ws + 22805248);    // 1032192 B
  unsigned short* out1 = (unsigned short*)(ws + 23837440);    // 21528576 B (end ~45.4 MB)

  hipMemsetAsync(fc1_acc, 0, 256 * 256 * sizeof(float), stream);

  k_wsum<<<64, 256, 0, stream>>>(adj, eidx, wsum);
  k_S<<<1, 512, 0, stream>>>(eidx, wsum, S);
  k_h1<<<165, 256, 0, stream>>>(S, x, h1);
  k_h2<<<165, 256, 0, stream>>>(S, h1, h2);
  k_hc<<<165, 256, 0, stream>>>(h1, h2, cheb_w, hc);
  k_pad<<<43008, 256, 0, stream>>>(x, xpad);
  k_wdt<<<2016, 256, 0, stream>>>(cheb_w, wdt);
  k_gemm_main<<<dim3(128, 6), 256, 0, stream>>>(xpad, wdt, hc, cheb_b, bn1, out1);
  k_gemm_fc1<<<dim3(2, 2, 18), 256, 0, stream>>>(out1, fc1_w, fc1_acc);
  k_final<<<256, 256, 0, stream>>>(fc1_acc, fc1_b, bnf1, fc2_w, fc2_b, bnf2,
                                   fc3_w, fc3_b, bnf3, (float*)d_out);
}

// Round 3
// 384.495 us; speedup vs baseline: 1.1893x; 1.1893x over previous
//
#include <hip/hip_runtime.h>
#include <hip/hip_bf16.h>

#define EPSF 1e-5f

typedef __bf16 bf16x8 __attribute__((ext_vector_type(8)));
typedef float f32x4 __attribute__((ext_vector_type(4)));

__device__ __forceinline__ float softplus_f(float x) {
  return fmaxf(x, 0.0f) + log1pf(expf(-fabsf(x)));
}

__device__ __forceinline__ unsigned short f2bf_bits(float f) {
  union { float f; unsigned int u; } v; v.f = f;
  unsigned int u = v.u;
  unsigned int lsb = (u >> 16) & 1u;
  u += 0x7fffu + lsb;  // round-to-nearest-even
  return (unsigned short)(u >> 16);
}

__device__ __forceinline__ void gl2lds16(const void* g, void* l) {
  __builtin_amdgcn_global_load_lds((const __attribute__((address_space(1))) void*)g,
                                   (__attribute__((address_space(3))) void*)l,
                                   16, 0, 0);
}

// ---------------- graph prep ----------------
__global__ __launch_bounds__(256) void k_wsum(const float* __restrict__ adj,
                                              const int* __restrict__ eidx,
                                              float* __restrict__ wsum) {
  __shared__ float part[256];
  int g = blockIdx.x;
  int t = threadIdx.x;
  int el = t & 7;
  int e = g * 8 + el;
  int s = eidx[e], d = eidx[512 + e];
  int boff = t >> 3;
  float acc = 0.f;
  for (int i = 0; i < 8; i++) {
    int b = boff + 32 * i;
    int base = b * 4096;
    float w1 = adj[base + s * 64 + d];
    float w2 = adj[base + d * 64 + s];
    acc += fmaxf(w1, w2);
  }
  part[t] = acc;
  __syncthreads();
  if (t < 8) {
    float sum = 0.f;
    for (int i = t; i < 256; i += 8) sum += part[i];
    wsum[g * 8 + t] = sum;
  }
}

__global__ __launch_bounds__(512) void k_S(const int* __restrict__ eidx,
                                           const float* __restrict__ wsum,
                                           float* __restrict__ S) {
  __shared__ float deg[64];
  __shared__ float Ssh[4096];
  int t = threadIdx.x;
  if (t < 64) deg[t] = 0.f;
  for (int i = t; i < 4096; i += 512) Ssh[i] = 0.f;
  __syncthreads();
  int s = eidx[t], d = eidx[512 + t];
  float w = wsum[t];
  atomicAdd(&deg[s], w);
  __syncthreads();
  float ds = deg[s], dd = deg[d];
  float dis = ds > 0.f ? 1.0f / sqrtf(ds) : 0.f;
  float did = dd > 0.f ? 1.0f / sqrtf(dd) : 0.f;
  float coef = -dis * w * did;
  atomicAdd(&Ssh[d * 64 + s], coef);
  __syncthreads();
  for (int i = t; i < 4096; i += 512) S[i] = Ssh[i];
}

__global__ __launch_bounds__(256) void k_h1(const float* __restrict__ S,
                                            const float* __restrict__ x,
                                            float* __restrict__ h1) {
  int idx = blockIdx.x * 256 + threadIdx.x;
  if (idx >= 64 * 657) return;
  int i = idx / 657, f = idx - i * 657;
  float acc = 0.f;
  for (int j = 0; j < 64; j++) acc += S[i * 64 + j] * x[j * 657 + f];
  h1[idx] = acc;
}

__global__ __launch_bounds__(256) void k_h2(const float* __restrict__ S,
                                            const float* __restrict__ h1,
                                            float* __restrict__ h2) {
  int idx = blockIdx.x * 256 + threadIdx.x;
  if (idx >= 64 * 657) return;
  int i = idx / 657, f = idx - i * 657;
  float acc = 0.f;
  for (int j = 0; j < 64; j++) acc += S[i * 64 + j] * h1[j * 657 + f];
  h2[idx] = 2.f * acc;
}

__global__ __launch_bounds__(256) void k_hc(const float* __restrict__ h1,
                                            const float* __restrict__ h2,
                                            const float* __restrict__ cheb_w,
                                            float* __restrict__ hc) {
  int idx = blockIdx.x * 256 + threadIdx.x;
  if (idx >= 64 * 657) return;
  int i = idx / 657, f = idx - i * 657;
  const float* W1 = cheb_w + 657 * 657;
  const float* W2 = cheb_w + 2 * 657 * 657;
  float acc = 0.f;
  for (int k = 0; k < 657; k++) {
    acc += h1[i * 657 + k] * W1[k * 657 + f];
    acc += h2[i * 657 + k] * W2[k * 657 + f];
  }
  hc[idx] = acc;
}

// xf_pad: 16384 x 672 bf16, packed-pair stores (uint = 2 bf16)
__global__ __launch_bounds__(256) void k_pad(const float* __restrict__ x,
                                             unsigned int* __restrict__ xp) {
  int idx = blockIdx.x * 256 + threadIdx.x;  // 16384*336
  int rr = idx / 336, u = idx - rr * 336;
  int c0 = u * 2;
  float a = (c0 < 657) ? x[rr * 657 + c0] : 0.f;
  float b = (c0 + 1 < 657) ? x[rr * 657 + c0 + 1] : 0.f;
  xp[idx] = ((unsigned int)f2bf_bits(b) << 16) | (unsigned int)f2bf_bits(a);
}

// WdT_pad[n][k] = W0[k][n] - W2[k][n], 768 x 672 bf16, LDS-tiled transpose
__global__ __launch_bounds__(256) void k_wdt(const float* __restrict__ cheb_w,
                                             unsigned short* __restrict__ wt) {
  __shared__ float tile[64][65];
  int k0 = blockIdx.x * 64;  // 11 blocks (k < 672, guarded)
  int n0 = blockIdx.y * 64;  // 12 blocks (n < 768, guarded)
  int t = threadIdx.x;
  const float* W2 = cheb_w + 2 * 657 * 657;
#pragma unroll
  for (int i = 0; i < 16; i++) {
    int idx = i * 256 + t;
    int kk = idx >> 6, nn = idx & 63;
    int k = k0 + kk, n = n0 + nn;
    float v = 0.f;
    if (k < 657 && n < 657) v = cheb_w[k * 657 + n] - W2[k * 657 + n];
    tile[kk][nn] = v;
  }
  __syncthreads();
#pragma unroll
  for (int i = 0; i < 16; i++) {
    int idx = i * 256 + t;
    int nn = idx >> 6, kk = idx & 63;
    int k = k0 + kk, n = n0 + nn;
    if (k < 672 && n < 768) wt[n * 672 + k] = f2bf_bits(tile[kk][nn]);
  }
}

// Wt[n][k] = fc1_w[k][n] as bf16 : (42048 x 256 fp32) -> (256 x 42048 bf16)
__global__ __launch_bounds__(256) void k_wt1(const float* __restrict__ W,
                                             unsigned short* __restrict__ Wt) {
  __shared__ float tile[64][65];
  int k0 = blockIdx.x * 64;  // 657 blocks, exact
  int n0 = blockIdx.y * 64;  // 4 blocks, exact
  int t = threadIdx.x;
#pragma unroll
  for (int i = 0; i < 16; i++) {
    int idx = i * 256 + t;
    int kk = idx >> 6, nn = idx & 63;
    tile[kk][nn] = W[(size_t)(k0 + kk) * 256 + n0 + nn];
  }
  __syncthreads();
#pragma unroll
  for (int i = 0; i < 16; i++) {
    int idx = i * 256 + t;
    int nn = idx >> 6, kk = idx & 63;
    Wt[(size_t)(n0 + nn) * 42048 + k0 + kk] = f2bf_bits(tile[kk][nn]);
  }
}

// ---------------- main GEMM: out1 = bn1(softplus(xf@Wd + cheb_b [+ hc rows<64])) ----------------
__global__ __launch_bounds__(256) void k_gemm_main(
    const unsigned short* __restrict__ Ap,   // 16384 x 672 bf16
    const unsigned short* __restrict__ BT,   // 768 x 672 bf16
    const float* __restrict__ hc,            // 64 x 657
    const float* __restrict__ cheb_b,
    const float* __restrict__ bn1,           // 4 x 657
    unsigned short* __restrict__ out1) {     // 16384 x 657 bf16
  __shared__ __align__(16) unsigned short As[128 * 32];
  __shared__ __align__(16) unsigned short Bs[128 * 32];
  const int mBase = blockIdx.x * 128;
  const int nBase = blockIdx.y * 128;
  const int tid = threadIdx.x;
  const int wave = tid >> 6, lane = tid & 63;
  const int wm = (wave >> 1) * 64, wn = (wave & 1) * 64;
  const int q = lane >> 4, r = lane & 15;
  f32x4 acc[4][4] = {};
  for (int k0 = 0; k0 < 672; k0 += 32) {
#pragma unroll
    for (int i = 0; i < 2; i++) {
      int c = i * 256 + tid;
      int row = c >> 2, kg = (c & 3) * 8;
      gl2lds16(Ap + (size_t)(mBase + row) * 672 + k0 + kg, &As[c * 8]);
      gl2lds16(BT + (size_t)(nBase + row) * 672 + k0 + kg, &Bs[c * 8]);
    }
    __syncthreads();
    bf16x8 a[4], b[4];
#pragma unroll
    for (int mi = 0; mi < 4; mi++)
      a[mi] = *(const bf16x8*)&As[(wm + mi * 16 + r) * 32 + q * 8];
#pragma unroll
    for (int ni = 0; ni < 4; ni++)
      b[ni] = *(const bf16x8*)&Bs[(wn + ni * 16 + r) * 32 + q * 8];
#pragma unroll
    for (int mi = 0; mi < 4; mi++)
#pragma unroll
      for (int ni = 0; ni < 4; ni++)
        acc[mi][ni] = __builtin_amdgcn_mfma_f32_16x16x32_bf16(a[mi], b[ni], acc[mi][ni], 0, 0, 0);
    __syncthreads();
  }
#pragma unroll
  for (int ni = 0; ni < 4; ni++) {
    int f = nBase + wn + ni * 16 + r;
    if (f >= 657) continue;
    float cb = cheb_b[f];
    float g1 = bn1[f], b1 = bn1[657 + f];
    float m1 = bn1[2 * 657 + f], v1 = bn1[3 * 657 + f];
    float inv = 1.0f / sqrtf(v1 + EPSF);
#pragma unroll
    for (int mi = 0; mi < 4; mi++) {
#pragma unroll
      for (int p = 0; p < 4; p++) {
        int row = mBase + wm + mi * 16 + q * 4 + p;
        float v = acc[mi][ni][p] + cb;
        if (row < 64) v += hc[row * 657 + f];
        v = softplus_f(v);
        v = g1 * (v - m1) * inv + b1;
        out1[(size_t)row * 657 + f] = f2bf_bits(v);
      }
    }
  }
}

// ---------------- fc1 GEMM split-K: Cacc += out1(256x42048) @ Wt^T ----------------
__global__ __launch_bounds__(256) void k_gemm_fc1(
    const unsigned short* __restrict__ A,    // 256 x 42048 bf16
    const unsigned short* __restrict__ Bt,   // 256 x 42048 bf16 (Wt)
    float* __restrict__ Cacc) {              // 256 x 256, pre-zeroed
  __shared__ __align__(16) unsigned short As[128 * 32];
  __shared__ __align__(16) unsigned short Bs[128 * 32];
  const int mBase = blockIdx.x * 128;
  const int nBase = blockIdx.y * 128;
  const int kc0 = blockIdx.z * 576;  // 73 * 576 = 42048
  const int tid = threadIdx.x;
  const int wave = tid >> 6, lane = tid & 63;
  const int wm = (wave >> 1) * 64, wn = (wave & 1) * 64;
  const int q = lane >> 4, r = lane & 15;
  f32x4 acc[4][4] = {};
  for (int kt = 0; kt < 18; kt++) {
    int k0 = kc0 + kt * 32;
#pragma unroll
    for (int i = 0; i < 2; i++) {
      int c = i * 256 + tid;
      int row = c >> 2, kg = (c & 3) * 8;
      gl2lds16(A + (size_t)(mBase + row) * 42048 + k0 + kg, &As[c * 8]);
      gl2lds16(Bt + (size_t)(nBase + row) * 42048 + k0 + kg, &Bs[c * 8]);
    }
    __syncthreads();
    bf16x8 a[4], b[4];
#pragma unroll
    for (int mi = 0; mi < 4; mi++)
      a[mi] = *(const bf16x8*)&As[(wm + mi * 16 + r) * 32 + q * 8];
#pragma unroll
    for (int ni = 0; ni < 4; ni++)
      b[ni] = *(const bf16x8*)&Bs[(wn + ni * 16 + r) * 32 + q * 8];
#pragma unroll
    for (int mi = 0; mi < 4; mi++)
#pragma unroll
      for (int ni = 0; ni < 4; ni++)
        acc[mi][ni] = __builtin_amdgcn_mfma_f32_16x16x32_bf16(a[mi], b[ni], acc[mi][ni], 0, 0, 0);
    __syncthreads();
  }
#pragma unroll
  for (int ni = 0; ni < 4; ni++) {
    int col = nBase + wn + ni * 16 + r;
#pragma unroll
    for (int mi = 0; mi < 4; mi++)
#pragma unroll
      for (int p = 0; p < 4; p++) {
        int row = mBase + wm + mi * 16 + q * 4 + p;
        atomicAdd(&Cacc[row * 256 + col], acc[mi][ni][p]);
      }
  }
}

// ---------------- tail ----------------
__global__ __launch_bounds__(256) void k_final(
    const float* __restrict__ Cacc,
    const float* __restrict__ fc1_b,
    const float* __restrict__ bnf1,
    const float* __restrict__ fc2_w,
    const float* __restrict__ fc2_b,
    const float* __restrict__ bnf2,
    const float* __restrict__ fc3_w,
    const float* __restrict__ fc3_b,
    const float* __restrict__ bnf3,
    float* __restrict__ out) {
  __shared__ float a1[256];
  __shared__ float a2[32];
  __shared__ float z[4];
  int b = blockIdx.x, t = threadIdx.x;
  {
    float v = Cacc[b * 256 + t] + fc1_b[t];
    v = softplus_f(v);
    float g = bnf1[t], bb = bnf1[256 + t];
    float m = bnf1[512 + t], vv = bnf1[768 + t];
    a1[t] = g * (v - m) / sqrtf(vv + EPSF) + bb;
  }
  __syncthreads();
  if (t < 32) {
    float s = fc2_b[t];
    for (int k = 0; k < 256; k++) s += a1[k] * fc2_w[k * 32 + t];
    s = softplus_f(s);
    float g = bnf2[t], bb = bnf2[32 + t];
    float m = bnf2[64 + t], vv = bnf2[96 + t];
    a2[t] = g * (s - m) / sqrtf(vv + EPSF) + bb;
  }
  __syncthreads();
  if (t < 4) {
    float s = fc3_b[t];
    for (int k = 0; k < 32; k++) s += a2[k] * fc3_w[k * 4 + t];
    float g = bnf3[t], bb = bnf3[4 + t];
    float m = bnf3[8 + t], vv = bnf3[12 + t];
    s = g * (s - m) / sqrtf(vv + EPSF) + bb;
    z[t] = softplus_f(s);
  }
  __syncthreads();
  if (t == 0) {
    float mx = fmaxf(fmaxf(z[0], z[1]), fmaxf(z[2], z[3]));
    float e0 = expf(z[0] - mx), e1 = expf(z[1] - mx);
    float e2 = expf(z[2] - mx), e3 = expf(z[3] - mx);
    float inv = 1.0f / (e0 + e1 + e2 + e3);
    out[b * 4 + 0] = e0 * inv;
    out[b * 4 + 1] = e1 * inv;
    out[b * 4 + 2] = e2 * inv;
    out[b * 4 + 3] = e3 * inv;
  }
}

extern "C" void kernel_launch(void* const* d_in, const int* in_sizes, int n_in,
                              void* d_out, int out_size, void* d_ws, size_t ws_size,
                              hipStream_t stream) {
  const float* x      = (const float*)d_in[0];
  const float* adj    = (const float*)d_in[1];
  const int*   eidx   = (const int*)d_in[2];
  const float* cheb_w = (const float*)d_in[3];
  const float* cheb_b = (const float*)d_in[4];
  const float* fc1_w  = (const float*)d_in[5];
  const float* fc1_b  = (const float*)d_in[6];
  const float* fc2_w  = (const float*)d_in[7];
  const float* fc2_b  = (const float*)d_in[8];
  const float* fc3_w  = (const float*)d_in[9];
  const float* fc3_b  = (const float*)d_in[10];
  const float* bn1    = (const float*)d_in[11];
  const float* bnf1   = (const float*)d_in[12];
  const float* bnf2   = (const float*)d_in[13];
  const float* bnf3   = (const float*)d_in[14];

  char* ws = (char*)d_ws;
  float* S       = (float*)(ws + 0);          // 16384 B
  float* wsum    = (float*)(ws + 16384);      // 2048 B
  float* h1      = (float*)(ws + 18432);      // 168192 B
  float* h2      = (float*)(ws + 186624);     // 168192 B
  float* hc      = (float*)(ws + 354816);     // 168192 B
  float* fc1_acc = (float*)(ws + 523008);     // 262144 B
  unsigned short* xpad = (unsigned short*)(ws + 785152);      // 22020096 B
  unsigned short* wdt  = (unsigned short*)(ws + 22805248);    // 1032192 B
  unsigned short* out1 = (unsigned short*)(ws + 23837440);    // 21528576 B (end ~45.4 MB)
  // Wt aliases xpad: xpad is dead once k_gemm_main completes, and Wt (21.53 MB)
  // fits in xpad's 22.02 MB. Stream order guarantees k_wt1 runs after k_gemm_main.
  unsigned short* Wt = xpad;

  hipMemsetAsync(fc1_acc, 0, 256 * 256 * sizeof(float), stream);

  k_wsum<<<64, 256, 0, stream>>>(adj, eidx, wsum);
  k_S<<<1, 512, 0, stream>>>(eidx, wsum, S);
  k_h1<<<165, 256, 0, stream>>>(S, x, h1);
  k_h2<<<165, 256, 0, stream>>>(S, h1, h2);
  k_hc<<<165, 256, 0, stream>>>(h1, h2, cheb_w, hc);
  k_pad<<<21504, 256, 0, stream>>>(x, (unsigned int*)xpad);
  k_wdt<<<dim3(11, 12), 256, 0, stream>>>(cheb_w, wdt);
  k_gemm_main<<<dim3(128, 6), 256, 0, stream>>>(xpad, wdt, hc, cheb_b, bn1, out1);
  k_wt1<<<dim3(657, 4), 256, 0, stream>>>(fc1_w, Wt);
  k_gemm_fc1<<<dim3(2, 2, 73), 256, 0, stream>>>(out1, Wt, fc1_acc);
  k_final<<<256, 256, 0, stream>>>(fc1_acc, fc1_b, bnf1, fc2_w, fc2_b, bnf2,
                                   fc3_w, fc3_b, bnf3, (float*)d_out);
}

// Round 4
// 319.381 us; speedup vs baseline: 1.4318x; 1.2039x over previous
//
#include <hip/hip_runtime.h>
#include <hip/hip_bf16.h>

#define EPSF 1e-5f

typedef __bf16 bf16x8 __attribute__((ext_vector_type(8)));
typedef float f32x4 __attribute__((ext_vector_type(4)));

__device__ __forceinline__ float softplus_f(float x) {
  return fmaxf(x, 0.0f) + log1pf(expf(-fabsf(x)));
}

__device__ __forceinline__ unsigned short f2bf_bits(float f) {
  union { float f; unsigned int u; } v; v.f = f;
  unsigned int u = v.u;
  unsigned int lsb = (u >> 16) & 1u;
  u += 0x7fffu + lsb;  // round-to-nearest-even
  return (unsigned short)(u >> 16);
}

__device__ __forceinline__ void gl2lds16(const void* g, void* l) {
  __builtin_amdgcn_global_load_lds((const __attribute__((address_space(1))) void*)g,
                                   (__attribute__((address_space(3))) void*)l,
                                   16, 0, 0);
}

// ---------------- graph prep ----------------
__global__ __launch_bounds__(256) void k_wsum(const float* __restrict__ adj,
                                              const int* __restrict__ eidx,
                                              float* __restrict__ wsum) {
  __shared__ float part[256];
  int g = blockIdx.x;
  int t = threadIdx.x;
  int el = t & 7;
  int e = g * 8 + el;
  int s = eidx[e], d = eidx[512 + e];
  int boff = t >> 3;
  float acc = 0.f;
  for (int i = 0; i < 8; i++) {
    int b = boff + 32 * i;
    int base = b * 4096;
    float w1 = adj[base + s * 64 + d];
    float w2 = adj[base + d * 64 + s];
    acc += fmaxf(w1, w2);
  }
  part[t] = acc;
  __syncthreads();
  if (t < 8) {
    float sum = 0.f;
    for (int i = t; i < 256; i += 8) sum += part[i];
    wsum[g * 8 + t] = sum;
  }
}

__global__ __launch_bounds__(512) void k_S(const int* __restrict__ eidx,
                                           const float* __restrict__ wsum,
                                           float* __restrict__ S) {
  __shared__ float deg[64];
  __shared__ float Ssh[4096];
  int t = threadIdx.x;
  if (t < 64) deg[t] = 0.f;
  for (int i = t; i < 4096; i += 512) Ssh[i] = 0.f;
  __syncthreads();
  int s = eidx[t], d = eidx[512 + t];
  float w = wsum[t];
  atomicAdd(&deg[s], w);
  __syncthreads();
  float ds = deg[s], dd = deg[d];
  float dis = ds > 0.f ? 1.0f / sqrtf(ds) : 0.f;
  float did = dd > 0.f ? 1.0f / sqrtf(dd) : 0.f;
  float coef = -dis * w * did;
  atomicAdd(&Ssh[d * 64 + s], coef);
  __syncthreads();
  for (int i = t; i < 4096; i += 512) S[i] = Ssh[i];
}

__global__ __launch_bounds__(256) void k_h1(const float* __restrict__ S,
                                            const float* __restrict__ x,
                                            float* __restrict__ h1) {
  int idx = blockIdx.x * 256 + threadIdx.x;
  if (idx >= 64 * 657) return;
  int i = idx / 657, f = idx - i * 657;
  float acc = 0.f;
  for (int j = 0; j < 64; j++) acc += S[i * 64 + j] * x[j * 657 + f];
  h1[idx] = acc;
}

__global__ __launch_bounds__(256) void k_h2(const float* __restrict__ S,
                                            const float* __restrict__ h1,
                                            float* __restrict__ h2) {
  int idx = blockIdx.x * 256 + threadIdx.x;
  if (idx >= 64 * 657) return;
  int i = idx / 657, f = idx - i * 657;
  float acc = 0.f;
  for (int j = 0; j < 64; j++) acc += S[i * 64 + j] * h1[j * 657 + f];
  h2[idx] = 2.f * acc;
}

// pack h12[64][1344] bf16 = [h1 | pad | h2 | pad]
__global__ __launch_bounds__(256) void k_pack_h12(const float* __restrict__ h1,
                                                  const float* __restrict__ h2,
                                                  unsigned short* __restrict__ h12) {
  int idx = blockIdx.x * 256 + threadIdx.x;  // 64*1344 = 86016
  int i = idx / 1344, k = idx - i * 1344;
  float v = 0.f;
  if (k < 657) v = h1[i * 657 + k];
  else if (k >= 672 && k < 1329) v = h2[i * 657 + (k - 672)];
  h12[idx] = f2bf_bits(v);
}

// BThc[n][gk] = gk<672 ? W1[gk][n] : W2[gk-672][n]  (bf16, zero-padded), 768 x 1344
__global__ __launch_bounds__(256) void k_bhc(const float* __restrict__ cheb_w,
                                             unsigned short* __restrict__ bt) {
  __shared__ float tile[64][65];
  int k0 = blockIdx.x * 64;  // 21 tiles
  int n0 = blockIdx.y * 64;  // 12 tiles
  int t = threadIdx.x;
  const float* W1 = cheb_w + 657 * 657;
  const float* W2 = cheb_w + 2 * 657 * 657;
#pragma unroll
  for (int i = 0; i < 16; i++) {
    int idx = i * 256 + t;
    int kk = idx >> 6, nn = idx & 63;
    int gk = k0 + kk, n = n0 + nn;
    float v = 0.f;
    if (n < 657) {
      if (gk < 672) {
        if (gk < 657) v = W1[gk * 657 + n];
      } else {
        int k2 = gk - 672;
        if (k2 < 657) v = W2[k2 * 657 + n];
      }
    }
    tile[kk][nn] = v;
  }
  __syncthreads();
#pragma unroll
  for (int i = 0; i < 16; i++) {
    int idx = i * 256 + t;
    int nn = idx >> 6, kk = idx & 63;
    int gk = k0 + kk, n = n0 + nn;
    bt[(size_t)n * 1344 + gk] = f2bf_bits(tile[kk][nn]);
  }
}

// hc(64x672 fp32, pre-zeroed) += h12(64x1344) @ BThc^T ; split-K via blockIdx.y
__global__ __launch_bounds__(256) void k_gemm_hc(
    const unsigned short* __restrict__ A,    // 64 x 1344 bf16
    const unsigned short* __restrict__ Bt,   // 768 x 1344 bf16
    float* __restrict__ hc) {                // 64 x 672 fp32
  __shared__ __align__(16) unsigned short As[64 * 32];
  __shared__ __align__(16) unsigned short Bs[128 * 32];
  const int nBase = blockIdx.x * 128;       // 6 tiles
  const int kc0 = blockIdx.y * 192;         // 7 splits x 6 iters
  const int tid = threadIdx.x;
  const int wave = tid >> 6, lane = tid & 63;
  const int wn = wave * 32;
  const int q = lane >> 4, r = lane & 15;
  f32x4 acc[4][2] = {};
  for (int kt = 0; kt < 6; kt++) {
    int k0 = kc0 + kt * 32;
    {
      int c = tid;
      int row = c >> 2, kg = (c & 3) * 8;
      gl2lds16(A + (size_t)row * 1344 + k0 + kg, &As[c * 8]);
    }
#pragma unroll
    for (int i = 0; i < 2; i++) {
      int c = i * 256 + tid;
      int row = c >> 2, kg = (c & 3) * 8;
      gl2lds16(Bt + (size_t)(nBase + row) * 1344 + k0 + kg, &Bs[c * 8]);
    }
    __syncthreads();
    bf16x8 a[4], b[2];
#pragma unroll
    for (int mi = 0; mi < 4; mi++)
      a[mi] = *(const bf16x8*)&As[(mi * 16 + r) * 32 + q * 8];
#pragma unroll
    for (int ni = 0; ni < 2; ni++)
      b[ni] = *(const bf16x8*)&Bs[(wn + ni * 16 + r) * 32 + q * 8];
#pragma unroll
    for (int mi = 0; mi < 4; mi++)
#pragma unroll
      for (int ni = 0; ni < 2; ni++)
        acc[mi][ni] = __builtin_amdgcn_mfma_f32_16x16x32_bf16(a[mi], b[ni], acc[mi][ni], 0, 0, 0);
    __syncthreads();
  }
#pragma unroll
  for (int ni = 0; ni < 2; ni++) {
    int f = nBase + wn + ni * 16 + r;
    if (f >= 672) continue;
#pragma unroll
    for (int mi = 0; mi < 4; mi++)
#pragma unroll
      for (int p = 0; p < 4; p++) {
        int row = mi * 16 + q * 4 + p;
        atomicAdd(&hc[row * 672 + f], acc[mi][ni][p]);
      }
  }
}

// xf_pad: 16384 x 672 bf16, packed-pair stores (uint = 2 bf16)
__global__ __launch_bounds__(256) void k_pad(const float* __restrict__ x,
                                             unsigned int* __restrict__ xp) {
  int idx = blockIdx.x * 256 + threadIdx.x;  // 16384*336
  int rr = idx / 336, u = idx - rr * 336;
  int c0 = u * 2;
  float a = (c0 < 657) ? x[rr * 657 + c0] : 0.f;
  float b = (c0 + 1 < 657) ? x[rr * 657 + c0 + 1] : 0.f;
  xp[idx] = ((unsigned int)f2bf_bits(b) << 16) | (unsigned int)f2bf_bits(a);
}

// WdT_pad[n][k] = W0[k][n] - W2[k][n], 768 x 672 bf16, LDS-tiled transpose
__global__ __launch_bounds__(256) void k_wdt(const float* __restrict__ cheb_w,
                                             unsigned short* __restrict__ wt) {
  __shared__ float tile[64][65];
  int k0 = blockIdx.x * 64;
  int n0 = blockIdx.y * 64;
  int t = threadIdx.x;
  const float* W2 = cheb_w + 2 * 657 * 657;
#pragma unroll
  for (int i = 0; i < 16; i++) {
    int idx = i * 256 + t;
    int kk = idx >> 6, nn = idx & 63;
    int k = k0 + kk, n = n0 + nn;
    float v = 0.f;
    if (k < 657 && n < 657) v = cheb_w[k * 657 + n] - W2[k * 657 + n];
    tile[kk][nn] = v;
  }
  __syncthreads();
#pragma unroll
  for (int i = 0; i < 16; i++) {
    int idx = i * 256 + t;
    int nn = idx >> 6, kk = idx & 63;
    int k = k0 + kk, n = n0 + nn;
    if (k < 672 && n < 768) wt[n * 672 + k] = f2bf_bits(tile[kk][nn]);
  }
}

// Wt[n][k] = fc1_w[k][n] as bf16 : (42048 x 256 fp32) -> (256 x 42048 bf16)
__global__ __launch_bounds__(256) void k_wt1(const float* __restrict__ W,
                                             unsigned short* __restrict__ Wt) {
  __shared__ float tile[64][65];
  int k0 = blockIdx.x * 64;  // 657 blocks, exact
  int n0 = blockIdx.y * 64;  // 4 blocks, exact
  int t = threadIdx.x;
#pragma unroll
  for (int i = 0; i < 16; i++) {
    int idx = i * 256 + t;
    int kk = idx >> 6, nn = idx & 63;
    tile[kk][nn] = W[(size_t)(k0 + kk) * 256 + n0 + nn];
  }
  __syncthreads();
#pragma unroll
  for (int i = 0; i < 16; i++) {
    int idx = i * 256 + t;
    int nn = idx >> 6, kk = idx & 63;
    Wt[(size_t)(n0 + nn) * 42048 + k0 + kk] = f2bf_bits(tile[kk][nn]);
  }
}

// ---------------- main GEMM: out1 = bn1(softplus(xf@Wd + cheb_b [+ hc rows<64])) ----------------
__global__ __launch_bounds__(256) void k_gemm_main(
    const unsigned short* __restrict__ Ap,   // 16384 x 672 bf16
    const unsigned short* __restrict__ BT,   // 768 x 672 bf16
    const float* __restrict__ hc,            // 64 x 672
    const float* __restrict__ cheb_b,
    const float* __restrict__ bn1,           // 4 x 657
    unsigned short* __restrict__ out1) {     // 16384 x 657 bf16
  __shared__ __align__(16) unsigned short As[128 * 32];
  __shared__ __align__(16) unsigned short Bs[128 * 32];
  const int mBase = blockIdx.x * 128;
  const int nBase = blockIdx.y * 128;
  const int tid = threadIdx.x;
  const int wave = tid >> 6, lane = tid & 63;
  const int wm = (wave >> 1) * 64, wn = (wave & 1) * 64;
  const int q = lane >> 4, r = lane & 15;
  f32x4 acc[4][4] = {};
  for (int k0 = 0; k0 < 672; k0 += 32) {
#pragma unroll
    for (int i = 0; i < 2; i++) {
      int c = i * 256 + tid;
      int row = c >> 2, kg = (c & 3) * 8;
      gl2lds16(Ap + (size_t)(mBase + row) * 672 + k0 + kg, &As[c * 8]);
      gl2lds16(BT + (size_t)(nBase + row) * 672 + k0 + kg, &Bs[c * 8]);
    }
    __syncthreads();
    bf16x8 a[4], b[4];
#pragma unroll
    for (int mi = 0; mi < 4; mi++)
      a[mi] = *(const bf16x8*)&As[(wm + mi * 16 + r) * 32 + q * 8];
#pragma unroll
    for (int ni = 0; ni < 4; ni++)
      b[ni] = *(const bf16x8*)&Bs[(wn + ni * 16 + r) * 32 + q * 8];
#pragma unroll
    for (int mi = 0; mi < 4; mi++)
#pragma unroll
      for (int ni = 0; ni < 4; ni++)
        acc[mi][ni] = __builtin_amdgcn_mfma_f32_16x16x32_bf16(a[mi], b[ni], acc[mi][ni], 0, 0, 0);
    __syncthreads();
  }
#pragma unroll
  for (int ni = 0; ni < 4; ni++) {
    int f = nBase + wn + ni * 16 + r;
    if (f >= 657) continue;
    float cb = cheb_b[f];
    float g1 = bn1[f], b1 = bn1[657 + f];
    float m1 = bn1[2 * 657 + f], v1 = bn1[3 * 657 + f];
    float inv = 1.0f / sqrtf(v1 + EPSF);
#pragma unroll
    for (int mi = 0; mi < 4; mi++) {
#pragma unroll
      for (int p = 0; p < 4; p++) {
        int row = mBase + wm + mi * 16 + q * 4 + p;
        float v = acc[mi][ni][p] + cb;
        if (row < 64) v += hc[row * 672 + f];
        v = softplus_f(v);
        v = g1 * (v - m1) * inv + b1;
        out1[(size_t)row * 657 + f] = f2bf_bits(v);
      }
    }
  }
}

// ---------------- fc1 GEMM split-K: Cacc += out1(256x42048) @ Wt^T ----------------
__global__ __launch_bounds__(256) void k_gemm_fc1(
    const unsigned short* __restrict__ A,    // 256 x 42048 bf16
    const unsigned short* __restrict__ Bt,   // 256 x 42048 bf16 (Wt)
    float* __restrict__ Cacc) {              // 256 x 256, pre-zeroed
  __shared__ __align__(16) unsigned short As[128 * 32];
  __shared__ __align__(16) unsigned short Bs[128 * 32];
  const int mBase = blockIdx.x * 128;
  const int nBase = blockIdx.y * 128;
  const int kc0 = blockIdx.z * 576;  // 73 * 576 = 42048
  const int tid = threadIdx.x;
  const int wave = tid >> 6, lane = tid & 63;
  const int wm = (wave >> 1) * 64, wn = (wave & 1) * 64;
  const int q = lane >> 4, r = lane & 15;
  f32x4 acc[4][4] = {};
  for (int kt = 0; kt < 18; kt++) {
    int k0 = kc0 + kt * 32;
#pragma unroll
    for (int i = 0; i < 2; i++) {
      int c = i * 256 + tid;
      int row = c >> 2, kg = (c & 3) * 8;
      gl2lds16(A + (size_t)(mBase + row) * 42048 + k0 + kg, &As[c * 8]);
      gl2lds16(Bt + (size_t)(nBase + row) * 42048 + k0 + kg, &Bs[c * 8]);
    }
    __syncthreads();
    bf16x8 a[4], b[4];
#pragma unroll
    for (int mi = 0; mi < 4; mi++)
      a[mi] = *(const bf16x8*)&As[(wm + mi * 16 + r) * 32 + q * 8];
#pragma unroll
    for (int ni = 0; ni < 4; ni++)
      b[ni] = *(const bf16x8*)&Bs[(wn + ni * 16 + r) * 32 + q * 8];
#pragma unroll
    for (int mi = 0; mi < 4; mi++)
#pragma unroll
      for (int ni = 0; ni < 4; ni++)
        acc[mi][ni] = __builtin_amdgcn_mfma_f32_16x16x32_bf16(a[mi], b[ni], acc[mi][ni], 0, 0, 0);
    __syncthreads();
  }
#pragma unroll
  for (int ni = 0; ni < 4; ni++) {
    int col = nBase + wn + ni * 16 + r;
#pragma unroll
    for (int mi = 0; mi < 4; mi++)
#pragma unroll
      for (int p = 0; p < 4; p++) {
        int row = mBase + wm + mi * 16 + q * 4 + p;
        atomicAdd(&Cacc[row * 256 + col], acc[mi][ni][p]);
      }
  }
}

// ---------------- tail ----------------
__global__ __launch_bounds__(256) void k_final(
    const float* __restrict__ Cacc,
    const float* __restrict__ fc1_b,
    const float* __restrict__ bnf1,
    const float* __restrict__ fc2_w,
    const float* __restrict__ fc2_b,
    const float* __restrict__ bnf2,
    const float* __restrict__ fc3_w,
    const float* __restrict__ fc3_b,
    const float* __restrict__ bnf3,
    float* __restrict__ out) {
  __shared__ float a1[256];
  __shared__ float a2[32];
  __shared__ float z[4];
  int b = blockIdx.x, t = threadIdx.x;
  {
    float v = Cacc[b * 256 + t] + fc1_b[t];
    v = softplus_f(v);
    float g = bnf1[t], bb = bnf1[256 + t];
    float m = bnf1[512 + t], vv = bnf1[768 + t];
    a1[t] = g * (v - m) / sqrtf(vv + EPSF) + bb;
  }
  __syncthreads();
  if (t < 32) {
    float s = fc2_b[t];
    for (int k = 0; k < 256; k++) s += a1[k] * fc2_w[k * 32 + t];
    s = softplus_f(s);
    float g = bnf2[t], bb = bnf2[32 + t];
    float m = bnf2[64 + t], vv = bnf2[96 + t];
    a2[t] = g * (s - m) / sqrtf(vv + EPSF) + bb;
  }
  __syncthreads();
  if (t < 4) {
    float s = fc3_b[t];
    for (int k = 0; k < 32; k++) s += a2[k] * fc3_w[k * 4 + t];
    float g = bnf3[t], bb = bnf3[4 + t];
    float m = bnf3[8 + t], vv = bnf3[12 + t];
    s = g * (s - m) / sqrtf(vv + EPSF) + bb;
    z[t] = softplus_f(s);
  }
  __syncthreads();
  if (t == 0) {
    float mx = fmaxf(fmaxf(z[0], z[1]), fmaxf(z[2], z[3]));
    float e0 = expf(z[0] - mx), e1 = expf(z[1] - mx);
    float e2 = expf(z[2] - mx), e3 = expf(z[3] - mx);
    float inv = 1.0f / (e0 + e1 + e2 + e3);
    out[b * 4 + 0] = e0 * inv;
    out[b * 4 + 1] = e1 * inv;
    out[b * 4 + 2] = e2 * inv;
    out[b * 4 + 3] = e3 * inv;
  }
}

extern "C" void kernel_launch(void* const* d_in, const int* in_sizes, int n_in,
                              void* d_out, int out_size, void* d_ws, size_t ws_size,
                              hipStream_t stream) {
  const float* x      = (const float*)d_in[0];
  const float* adj    = (const float*)d_in[1];
  const int*   eidx   = (const int*)d_in[2];
  const float* cheb_w = (const float*)d_in[3];
  const float* cheb_b = (const float*)d_in[4];
  const float* fc1_w  = (const float*)d_in[5];
  const float* fc1_b  = (const float*)d_in[6];
  const float* fc2_w  = (const float*)d_in[7];
  const float* fc2_b  = (const float*)d_in[8];
  const float* fc3_w  = (const float*)d_in[9];
  const float* fc3_b  = (const float*)d_in[10];
  const float* bn1    = (const float*)d_in[11];
  const float* bnf1   = (const float*)d_in[12];
  const float* bnf2   = (const float*)d_in[13];
  const float* bnf3   = (const float*)d_in[14];

  char* ws = (char*)d_ws;
  float* S       = (float*)(ws + 0);          // 16384 B
  float* wsum    = (float*)(ws + 16384);      // 2048 B
  float* h1      = (float*)(ws + 18432);      // 168192 B
  float* h2      = (float*)(ws + 186624);     // 168192 B
  float* hc      = (float*)(ws + 354816);     // 172032 B (64 x 672 fp32)
  float* fc1_acc = (float*)(ws + 526848);     // 262144 B
  unsigned short* xpad = (unsigned short*)(ws + 788992);      // 22020096 B
  unsigned short* wdt  = (unsigned short*)(ws + 22809088);    // 1032192 B
  unsigned short* out1 = (unsigned short*)(ws + 23841280);    // 21528576 B (end ~45.4 MB)
  // Wt aliases xpad (dead after k_gemm_main).
  unsigned short* Wt = xpad;
  // h12/BThc alias xpad too: they are consumed by k_gemm_hc BEFORE k_pad
  // overwrites the region (stream order).
  unsigned short* h12  = xpad;                          // 172032 B
  unsigned short* BThc = (unsigned short*)((char*)xpad + 172032);  // 2064384 B

  hipMemsetAsync(fc1_acc, 0, 256 * 256 * sizeof(float), stream);
  hipMemsetAsync(hc, 0, 64 * 672 * sizeof(float), stream);

  k_wsum<<<64, 256, 0, stream>>>(adj, eidx, wsum);
  k_S<<<1, 512, 0, stream>>>(eidx, wsum, S);
  k_h1<<<165, 256, 0, stream>>>(S, x, h1);
  k_h2<<<165, 256, 0, stream>>>(S, h1, h2);
  k_pack_h12<<<336, 256, 0, stream>>>(h1, h2, h12);
  k_bhc<<<dim3(21, 12), 256, 0, stream>>>(cheb_w, BThc);
  k_gemm_hc<<<dim3(6, 7), 256, 0, stream>>>(h12, BThc, hc);
  k_pad<<<21504, 256, 0, stream>>>(x, (unsigned int*)xpad);
  k_wdt<<<dim3(11, 12), 256, 0, stream>>>(cheb_w, wdt);
  k_gemm_main<<<dim3(128, 6), 256, 0, stream>>>(xpad, wdt, hc, cheb_b, bn1, out1);
  k_wt1<<<dim3(657, 4), 256, 0, stream>>>(fc1_w, Wt);
  k_gemm_fc1<<<dim3(2, 2, 73), 256, 0, stream>>>(out1, Wt, fc1_acc);
  k_final<<<256, 256, 0, stream>>>(fc1_acc, fc1_b, bnf1, fc2_w, fc2_b, bnf2,
                                   fc3_w, fc3_b, bnf3, (float*)d_out);
}